// Round 4
// baseline (443.393 us; speedup 1.0000x reference)
//
#include <hip/hip_runtime.h>

#define APAD 65

// ---------------- Prep: pack centroids as (x, y, z, 0.5*|c|^2) ----------------
__global__ __launch_bounds__(256) void fp_prep(
    const float* __restrict__ cents, float4* __restrict__ pk, int M)
{
    int m = blockIdx.x * 256 + threadIdx.x;
    if (m < M) {
        float x = cents[3*m], y = cents[3*m+1], z = cents[3*m+2];
        pk[m] = make_float4(x, y, z, 0.5f * (x*x + y*y + z*z));
    }
}

__device__ __forceinline__ float sdist(float vx, float vy, float vz, float4 c)
{
    return fmaf(-vx, c.x, fmaf(-vy, c.y, fmaf(-vz, c.z, c.w)));
}

// value-only sorted-triple insert (5 ops)
__device__ __forceinline__ void vmins3(float s, float& c0, float& c1, float& c2)
{
    float m0 = fmaxf(c0, s); c0 = fminf(c0, s);
    float m1 = fmaxf(c1, m0); c1 = fminf(c1, m0);
    c2 = fminf(c2, m1);
}

// exact (value,index) insert, strict < (earlier insert wins ties)
__device__ __forceinline__ void ins3(float e, int ei,
                                     float& c0, float& c1, float& c2,
                                     int& i0, int& i1, int& i2)
{
    bool l0 = e < c0, l1 = e < c1, l2 = e < c2;
    c2 = l1 ? c1 : (l2 ? e  : c2);
    i2 = l1 ? i1 : (l2 ? ei : i2);
    c1 = l0 ? c0 : (l1 ? e  : c1);
    i1 = l0 ? i0 : (l1 ? ei : i1);
    c0 = l0 ? e  : c0;
    i0 = l0 ? ei : i0;
}

// insert with index tiebreak (smaller index wins on equal value)
__device__ __forceinline__ void ins3t(float e, int ei,
                                      float& c0, float& c1, float& c2,
                                      int& i0, int& i1, int& i2)
{
    bool l0 = (e < c0) || (e == c0 && ei < i0);
    bool l1 = (e < c1) || (e == c1 && ei < i1);
    bool l2 = (e < c2) || (e == c2 && ei < i2);
    c2 = l1 ? c1 : (l2 ? e  : c2);
    i2 = l1 ? i1 : (l2 ? ei : i2);
    c1 = l0 ? c0 : (l1 ? e  : c1);
    i1 = l0 ? i0 : (l1 ? ei : i1);
    c0 = l0 ? e  : c0;
    i0 = l0 ? ei : i0;
}

// ---------------- Kernel A: KNN + IDW interp + Linear1 + partial BN stats ----------------
// Block = 256 thr = 4 waves = 2 vertex-groups of 64 (1 thread/vertex).
// Waves (grp, half): half scans centroids [half*M/2, (half+1)*M/2) with
// wave-uniform loads (scalar stream, no LDS). Two-pass top-3.
__global__ __launch_bounds__(256) void fp_main(
    const float* __restrict__ verts,
    const float4* __restrict__ pk,
    const float* __restrict__ feats,
    const float* __restrict__ W1,
    const float* __restrict__ b1,
    float* __restrict__ hT,
    float* __restrict__ partials,
    int N, int M)
{
    __shared__ float interpL[128 * APAD];   // scratch during KNN, [128][APAD] after
    __shared__ float c2gS[128];
    __shared__ int   widx[2][64][3];
    __shared__ float wwt [2][64][3];
    __shared__ float statsL[256];

    int t = threadIdx.x, lane = t & 63, wave = t >> 6;
    int grp = wave >> 1, half = wave & 1;
    int mhalf = M >> 1;
    int mbase = __builtin_amdgcn_readfirstlane(half * mhalf);

    int vb0 = blockIdx.x * 128;
    int vtx = vb0 + grp * 64 + lane;
    int vs  = vtx < N ? vtx : N - 1;
    float vx = verts[3*vs], vy = verts[3*vs+1], vz = verts[3*vs+2];

    // ---- pass 1: values only ----
    float c0 = 3.4e38f, c1 = 3.4e38f, c2 = 3.4e38f;
    #pragma unroll 4
    for (int i = 0; i < mhalf; ++i) {
        float s = sdist(vx, vy, vz, pk[mbase + i]);
        vmins3(s, c0, c1, c2);
    }

    float* mrgv = interpL;                    // [2][3][64] scratch
    if (half == 1) {
        mrgv[(grp*3+0)*64 + lane] = c0;
        mrgv[(grp*3+1)*64 + lane] = c1;
        mrgv[(grp*3+2)*64 + lane] = c2;
    }
    __syncthreads();                          // B1
    if (half == 0) {
        vmins3(mrgv[(grp*3+0)*64 + lane], c0, c1, c2);
        vmins3(mrgv[(grp*3+1)*64 + lane], c0, c1, c2);
        vmins3(mrgv[(grp*3+2)*64 + lane], c0, c1, c2);
        c2gS[grp*64 + lane] = c2;
    }
    __syncthreads();                          // B2
    float c2g = c2gS[grp*64 + lane];

    // ---- pass 2: collect exact (s, idx) candidates ----
    float f0 = 3.4e38f, f1 = 3.4e38f, f2 = 3.4e38f;
    int   j0 = 0x7fffffff, j1 = 0x7fffffff, j2 = 0x7fffffff;
    #pragma unroll 4
    for (int i = 0; i < mhalf; ++i) {
        int m = mbase + i;
        float s = sdist(vx, vy, vz, pk[m]);
        bool hit = (s <= c2g);
        if (__any(hit)) {
            if (hit) ins3(s, m, f0, f1, f2, j0, j1, j2);
        }
    }

    float* exv = interpL;                     // [2][3][64]
    int*   exi = (int*)(interpL + 512);       // [2][3][64]
    if (half == 1) {
        exv[(grp*3+0)*64 + lane] = f0; exi[(grp*3+0)*64 + lane] = j0;
        exv[(grp*3+1)*64 + lane] = f1; exi[(grp*3+1)*64 + lane] = j1;
        exv[(grp*3+2)*64 + lane] = f2; exi[(grp*3+2)*64 + lane] = j2;
    }
    __syncthreads();                          // B4
    if (half == 0) {
        ins3t(exv[(grp*3+0)*64+lane], exi[(grp*3+0)*64+lane], f0,f1,f2, j0,j1,j2);
        ins3t(exv[(grp*3+1)*64+lane], exi[(grp*3+1)*64+lane], f0,f1,f2, j0,j1,j2);
        ins3t(exv[(grp*3+2)*64+lane], exi[(grp*3+2)*64+lane], f0,f1,f2, j0,j1,j2);

        // exact d^2 + IDW weights (P=2 -> 1/d^2, no sqrt)
        float4 ca = pk[j0], cb = pk[j1], cc = pk[j2];
        float dx, dy, dz;
        dx = vx-ca.x; dy = vy-ca.y; dz = vz-ca.z;
        float d0 = fmaf(dx,dx, fmaf(dy,dy, dz*dz));
        dx = vx-cb.x; dy = vy-cb.y; dz = vz-cb.z;
        float d1 = fmaf(dx,dx, fmaf(dy,dy, dz*dz));
        dx = vx-cc.x; dy = vy-cc.y; dz = vz-cc.z;
        float d2 = fmaf(dx,dx, fmaf(dy,dy, dz*dz));

        bool z0 = (d0 == 0.0f), z1 = (d1 == 0.0f), z2 = (d2 == 0.0f);
        float w0, w1, w2;
        if (z0 || z1 || z2) {
            w0 = z0 ? 1.0f : 0.0f;
            w1 = z1 ? 1.0f : 0.0f;
            w2 = z2 ? 1.0f : 0.0f;
        } else {
            w0 = 1.0f / d0; w1 = 1.0f / d1; w2 = 1.0f / d2;
        }
        float winv = 1.0f / (w0 + w1 + w2);
        widx[grp][lane][0] = j0; wwt[grp][lane][0] = w0 * winv;
        widx[grp][lane][1] = j1; wwt[grp][lane][1] = w1 * winv;
        widx[grp][lane][2] = j2; wwt[grp][lane][2] = w2 * winv;
    }
    statsL[t] = 0.0f;
    __syncthreads();                          // B5

    // ---- gather: 2 threads per vertex, 32 feats each ----
    {
        int vloc = t >> 1;
        int fh = (t & 1) * 32;
        int g = vloc >> 6, vl = vloc & 63;
        int a0 = widx[g][vl][0], a1 = widx[g][vl][1], a2 = widx[g][vl][2];
        float u0 = wwt[g][vl][0], u1 = wwt[g][vl][1], u2 = wwt[g][vl][2];
        const float4* p0 = (const float4*)(feats + (size_t)a0 * 64 + fh);
        const float4* p1 = (const float4*)(feats + (size_t)a1 * 64 + fh);
        const float4* p2 = (const float4*)(feats + (size_t)a2 * 64 + fh);
        float* dst = interpL + vloc * APAD + fh;
        #pragma unroll
        for (int q = 0; q < 8; ++q) {
            float4 A = p0[q], B = p1[q], C = p2[q];
            dst[4*q+0] = fmaf(u0, A.x, fmaf(u1, B.x, u2*C.x));
            dst[4*q+1] = fmaf(u0, A.y, fmaf(u1, B.y, u2*C.y));
            dst[4*q+2] = fmaf(u0, A.z, fmaf(u1, B.z, u2*C.z));
            dst[4*q+3] = fmaf(u0, A.w, fmaf(u1, B.w, u2*C.w));
        }
    }
    __syncthreads();                          // B6

    // ---- GEMM1 (two 64-vertex groups) + partial BN stats ----
    int cw = __builtin_amdgcn_readfirstlane((t >> 6) << 5);
    for (int g = 0; g < 2; ++g) {
        float acc[32];
        #pragma unroll
        for (int j = 0; j < 32; ++j) acc[j] = b1[cw + j];
        const float* xrow = interpL + (g*64 + lane) * APAD;
        #pragma unroll 8
        for (int d = 0; d < 64; ++d) {
            float x = xrow[d];
            const float* wr = W1 + d * 128 + cw;
            #pragma unroll
            for (int j = 0; j < 32; ++j) acc[j] = fmaf(x, wr[j], acc[j]);
        }
        int gv = vb0 + g*64 + lane;
        bool valid = gv < N;
        if (valid) {
            #pragma unroll
            for (int j = 0; j < 32; ++j)
                hT[(size_t)(cw + j) * N + gv] = acc[j];
        }
        #pragma unroll
        for (int j = 0; j < 32; ++j) {
            float v  = valid ? acc[j] : 0.0f;
            float vq = v * v;
            #pragma unroll
            for (int o = 32; o; o >>= 1) {
                v  += __shfl_xor(v, o);
                vq += __shfl_xor(vq, o);
            }
            if (lane == 0) {
                statsL[cw + j]       += v;
                statsL[128 + cw + j] += vq;
            }
        }
    }
    __syncthreads();                          // B7
    partials[(size_t)blockIdx.x * 256 + t] = statsL[t];
}

// ---------------- Finalize: reduce partials -> BN scale/shift ----------------
__global__ __launch_bounds__(256) void fp_finalize(
    const float* __restrict__ partials,
    const float* __restrict__ gamma,
    const float* __restrict__ beta,
    float* __restrict__ ss, int nblk, int N)
{
    int t = threadIdx.x;
    float a0 = 0, a1 = 0, a2 = 0, a3 = 0;
    int i = 0;
    for (; i + 4 <= nblk; i += 4) {
        a0 += partials[(size_t)(i+0)*256 + t];
        a1 += partials[(size_t)(i+1)*256 + t];
        a2 += partials[(size_t)(i+2)*256 + t];
        a3 += partials[(size_t)(i+3)*256 + t];
    }
    for (; i < nblk; ++i) a0 += partials[(size_t)i*256 + t];
    __shared__ float sums[256];
    sums[t] = (a0 + a1) + (a2 + a3);
    __syncthreads();
    if (t < 128) {
        float inv = 1.0f / (float)N;
        float mu  = sums[t] * inv;
        float var = fmaf(-mu, mu, sums[128 + t] * inv);
        var = fmaxf(var, 0.0f);
        float is = rsqrtf(var + 1e-5f);
        float sc = gamma[t] * is;
        ss[t] = sc;
        ss[128 + t] = beta[t] - mu * sc;
    }
}

// ---------------- Kernel C: BN + ReLU + Linear2 ----------------
#define CST 68   // [k][r] stride: bank (4k+lane)%32 -> 2-way (free)

__global__ __launch_bounds__(256) void fp_bn_mlp2(
    const float* __restrict__ hT,
    const float* __restrict__ ss,
    const float* __restrict__ W2,
    const float* __restrict__ b2,
    float* __restrict__ out,
    int N)
{
    __shared__ float scS[128], shS[128];
    __shared__ float hl[128 * CST];   // phase2 reuse as [64][129]
    int t = threadIdx.x;
    if (t < 128) { scS[t] = ss[t]; shS[t] = ss[128 + t]; }
    __syncthreads();

    int r0 = blockIdx.x * 64;
    int N4 = N >> 2, r04 = r0 >> 2;
    const float4* hT4 = (const float4*)hT;

    #pragma unroll
    for (int jj = 0; jj < 8; ++jj) {
        int i4 = t + jj * 256;
        int k = i4 >> 4, r4 = i4 & 15;
        float4 v = make_float4(0.f, 0.f, 0.f, 0.f);
        if (r0 + 4*r4 < N) v = hT4[(size_t)k * N4 + r04 + r4];
        float sc = scS[k], sh = shS[k];
        float4 o;
        o.x = fmaxf(fmaf(v.x, sc, sh), 0.f);
        o.y = fmaxf(fmaf(v.y, sc, sh), 0.f);
        o.z = fmaxf(fmaf(v.z, sc, sh), 0.f);
        o.w = fmaxf(fmaf(v.w, sc, sh), 0.f);
        ((float4*)hl)[k * 17 + r4] = o;
    }
    __syncthreads();

    int lane = t & 63;
    int cw = __builtin_amdgcn_readfirstlane((t >> 6) << 5);
    float acc[32];
    #pragma unroll
    for (int j = 0; j < 32; ++j) acc[j] = b2[cw + j];
    #pragma unroll 4
    for (int k = 0; k < 128; ++k) {
        float x = hl[k * CST + lane];
        const float* wr = W2 + k * 128 + cw;
        #pragma unroll
        for (int j = 0; j < 32; ++j) acc[j] = fmaf(x, wr[j], acc[j]);
    }
    __syncthreads();

    // transpose via LDS for coalesced float4 stores
    #pragma unroll
    for (int j = 0; j < 32; ++j) hl[lane * 129 + cw + j] = acc[j];
    __syncthreads();

    #pragma unroll
    for (int jj = 0; jj < 8; ++jj) {
        int i4 = t + jj * 256;
        int r = i4 >> 5, cq = (i4 & 31) * 4;
        int row = r0 + r;
        if (row < N) {
            float4 o4 = make_float4(hl[r*129 + cq], hl[r*129 + cq + 1],
                                    hl[r*129 + cq + 2], hl[r*129 + cq + 3]);
            *(float4*)(out + (size_t)row * 128 + cq) = o4;
        }
    }
}

extern "C" void kernel_launch(void* const* d_in, const int* in_sizes, int n_in,
                              void* d_out, int out_size, void* d_ws, size_t ws_size,
                              hipStream_t stream)
{
    (void)n_in; (void)out_size; (void)ws_size;
    const float* verts = (const float*)d_in[0];
    const float* cents = (const float*)d_in[1];
    const float* feats = (const float*)d_in[2];
    const float* W1    = (const float*)d_in[3];
    const float* b1    = (const float*)d_in[4];
    const float* gamma = (const float*)d_in[5];
    const float* beta  = (const float*)d_in[6];
    const float* W2    = (const float*)d_in[7];
    const float* b2    = (const float*)d_in[8];
    float* out = (float*)d_out;

    int N = in_sizes[0] / 3;
    int M = in_sizes[1] / 3;

    float*  ss       = (float*)d_ws;                                  // 256 floats
    float4* pk       = (float4*)((char*)d_ws + 1024);                 // [M]
    float*  hT       = (float*)((char*)d_ws + 1024 + (size_t)M * 16); // [128,N]
    float*  partials = hT + (size_t)128 * N;                          // [nblkA,256]

    int nblkA = (N + 127) / 128;

    hipLaunchKernelGGL(fp_prep, dim3((M + 255) / 256), dim3(256), 0, stream,
                       cents, pk, M);

    hipLaunchKernelGGL(fp_main, dim3(nblkA), dim3(256), 0, stream,
                       verts, pk, feats, W1, b1, hT, partials, N, M);

    hipLaunchKernelGGL(fp_finalize, dim3(1), dim3(256), 0, stream,
                       partials, gamma, beta, ss, nblkA, N);

    int blocksC = (N + 63) / 64;
    hipLaunchKernelGGL(fp_bn_mlp2, dim3(blocksC), dim3(256), 0, stream,
                       hT, ss, W2, b2, out, N);
}